// Round 5
// baseline (152.896 us; speedup 1.0000x reference)
//
#include <hip/hip_runtime.h>

typedef __attribute__((ext_vector_type(8))) short short8;
typedef __attribute__((ext_vector_type(4))) float f32x4;
typedef __attribute__((ext_vector_type(4))) int   i32x4;
typedef unsigned long long u64;

#define NN 8192
#define FIN 128
#define FOUT 64
#define NT (NN / 64)          // 128 u64 mask words per row
#define LRELU_ALPHA 0.2f

__device__ __forceinline__ unsigned short f2bf(float x) {
    unsigned u = __float_as_uint(x);
    unsigned r = (u + 0x7FFFu + ((u >> 16) & 1u)) >> 16;  // RNE
    return (unsigned short)r;
}

// ---------------------------------------------------------------------------
// Kernel 1: h = inp @ W ; s1 = h@a1 ; s2 = h@a2 ;
//   ht[f][i] = bf16(h[i][f]) ; e1v[i]=exp(s2_i) ; e2v[i]=exp(alpha*s2_i)
// Natural column order (mask kernel emits natural bit order).
// ---------------------------------------------------------------------------
__global__ __launch_bounds__(256) void gat_prep(
    const float* __restrict__ inp, const float* __restrict__ W,
    const float* __restrict__ a,
    unsigned short* __restrict__ ht, float* __restrict__ s1, float* __restrict__ s2,
    float* __restrict__ e1v, float* __restrict__ e2v)
{
    __shared__ float Wl[FIN * FOUT];   // 32 KB
    __shared__ float il[4 * FIN];      // 2 KB
    const int t = threadIdx.x;
    const int i0 = blockIdx.x * 4;

    #pragma unroll
    for (int k = 0; k < (FIN * FOUT) / 256; ++k)
        Wl[t + 256 * k] = W[t + 256 * k];
    #pragma unroll
    for (int k = 0; k < (4 * FIN) / 256; ++k)
        il[t + 256 * k] = inp[(size_t)i0 * FIN + t + 256 * k];
    __syncthreads();

    const int r = t >> 6;        // local row 0..3
    const int f = t & 63;        // output feature
    float acc = 0.f;
    #pragma unroll 8
    for (int k = 0; k < FIN; ++k)
        acc = fmaf(il[r * FIN + k], Wl[k * FOUT + f], acc);

    float v1 = acc * a[f];
    float v2 = acc * a[FOUT + f];
    #pragma unroll
    for (int off = 32; off; off >>= 1) {
        v1 += __shfl_xor(v1, off, 64);
        v2 += __shfl_xor(v2, off, 64);
    }
    const int i = i0 + r;
    if (f == 0) {
        s1[i] = v1;
        s2[i] = v2;
        e1v[i] = __expf(v2);
        e2v[i] = __expf(LRELU_ALPHA * v2);
    }
    ht[(size_t)f * NN + i] = f2bf(acc);
}

// ---------------------------------------------------------------------------
// Kernel 2: s2max = max_j s2[j]
// ---------------------------------------------------------------------------
__global__ __launch_bounds__(1024) void gat_s2max(const float* __restrict__ s2,
                                                  float* __restrict__ s2m)
{
    __shared__ float red[16];
    float m = -1e30f;
    for (int idx = threadIdx.x; idx < NN; idx += 1024) m = fmaxf(m, s2[idx]);
    #pragma unroll
    for (int off = 32; off; off >>= 1) m = fmaxf(m, __shfl_xor(m, off, 64));
    if ((threadIdx.x & 63) == 0) red[threadIdx.x >> 6] = m;
    __syncthreads();
    if (threadIdx.x == 0) {
        float mm = red[0];
        #pragma unroll
        for (int k = 1; k < 16; ++k) mm = fmaxf(mm, red[k]);
        s2m[0] = mm;
    }
}

// ---------------------------------------------------------------------------
// Kernel 3: adj (256 MB int32) -> bitmask (8 MB), NATURAL bit order,
// ballot-free: one thread per 32-col word. 8 independent dwordx4 loads
// (128 B contiguous/thread), local bit-pack, one coalesced u32 store.
// 8192 blocks -> 32 waves/CU, ~256 KB/CU in flight.
// ---------------------------------------------------------------------------
__global__ __launch_bounds__(256) void gat_mask(const int* __restrict__ adj,
                                                unsigned* __restrict__ mask)
{
    const int gid = blockIdx.x * 256 + threadIdx.x;   // word index, 0 .. 2M-1
    const int* p = adj + (size_t)gid * 32;

    i32x4 v[8];
    #pragma unroll
    for (int q = 0; q < 8; ++q)
        v[q] = *(const i32x4*)(p + q * 4);

    unsigned m = 0;
    #pragma unroll
    for (int q = 0; q < 8; ++q) {
        #pragma unroll
        for (int e = 0; e < 4; ++e)
            m |= (v[q][e] > 0 ? 1u : 0u) << (q * 4 + e);
    }
    mask[gid] = m;
}

// ---------------------------------------------------------------------------
// Kernel 4 (hot): mask-driven attention, all operands L2-resident.
// Natural order; af pack via v_cvt_pk_bf16_f32; row-sum via ones-B MFMA.
// Block: 256 = 4 waves x 16 rows. Grid: (128, JS).
// ---------------------------------------------------------------------------
__global__ __launch_bounds__(256, 4) void gat_attn(
    const u64* __restrict__ mask, const unsigned short* __restrict__ ht,
    const float* __restrict__ s1, const float* __restrict__ e1v,
    const float* __restrict__ e2v, const float* __restrict__ s2m,
    float* __restrict__ pacc, float* __restrict__ pl, int jlen)
{
    const int w    = threadIdx.x >> 6;   // wave 0..3 -> rows w*16..w*16+15
    const int lane = threadIdx.x & 63;
    const int lo   = lane & 15;          // A-frag row / B-frag col
    const int kg   = lane >> 4;          // k-group 0..3
    const int i0   = blockIdx.x * 64;
    const int i    = i0 + w * 16 + lo;   // this lane's attention row

    const float s1v = s1[i];
    const float mm  = s1v + s2m[0];
    const float Mi  = fmaxf(mm, LRELU_ALPHA * mm);      // >= max_j e_ij
    const float c1  = __expf(s1v - Mi);
    const float c2  = __expf(LRELU_ALPHA * s1v - Mi);
    const float Er  = __expf(-s1v);                     // x>0  <=>  e1 > Er

    const u64* mrow = mask + (size_t)i * NT;
    const int tstart = (blockIdx.y * jlen) >> 6;
    const int tend   = tstart + (jlen >> 6);

    f32x4 acc0 = {0.f,0.f,0.f,0.f}, acc1 = {0.f,0.f,0.f,0.f};
    f32x4 acc2 = {0.f,0.f,0.f,0.f}, acc3 = {0.f,0.f,0.f,0.f};
    f32x4 accl = {0.f,0.f,0.f,0.f};

    // all-ones bf16 B fragment (1.0 = 0x3F80) for the row-sum accumulator
    short8 ones;
    #pragma unroll
    for (int e = 0; e < 8; ++e) ones[e] = (short)0x3F80;

    u64 mw = mrow[tstart];

    for (int t = tstart; t < tend; ++t) {
        const u64 mcur = mw;
        if (t + 1 < tend) mw = mrow[t + 1];            // prefetch next mask word

        const int jc = t << 6;
        #pragma unroll
        for (int s = 0; s < 2; ++s) {
            const unsigned mb = (unsigned)(mcur >> (32 * s + 8 * kg)) & 0xffu;
            const int vg = jc + 32 * s + 8 * kg;
            const f32x4 E1a = *(const f32x4*)(e1v + vg);
            const f32x4 E1b = *(const f32x4*)(e1v + vg + 4);
            const f32x4 E2a = *(const f32x4*)(e2v + vg);
            const f32x4 E2b = *(const f32x4*)(e2v + vg + 4);

            float p[8];
            #pragma unroll
            for (int e = 0; e < 8; ++e) {
                const float e1 = (e < 4) ? E1a[e] : E1b[e - 4];
                const float e2 = (e < 4) ? E2a[e] : E2b[e - 4];
                float pv = (e1 > Er) ? c1 * e1 : c2 * e2;
                pv = ((mb >> e) & 1u) ? pv : 0.f;
                p[e] = pv;
            }
            union { short8 s8; unsigned u[4]; } afu;
            #pragma unroll
            for (int q = 0; q < 4; ++q) {
                unsigned rr;
                asm("v_cvt_pk_bf16_f32 %0, %1, %2" : "=v"(rr) : "v"(p[2 * q]), "v"(p[2 * q + 1]));
                afu.u[q] = rr;
            }
            const short8 af = afu.s8;

            const unsigned short* hb = ht + vg;
            const short8 b0 = *(const short8*)(hb + (size_t)(0 * 16 + lo) * NN);
            const short8 b1 = *(const short8*)(hb + (size_t)(1 * 16 + lo) * NN);
            const short8 b2 = *(const short8*)(hb + (size_t)(2 * 16 + lo) * NN);
            const short8 b3 = *(const short8*)(hb + (size_t)(3 * 16 + lo) * NN);

            acc0 = __builtin_amdgcn_mfma_f32_16x16x32_bf16(af, b0, acc0, 0, 0, 0);
            acc1 = __builtin_amdgcn_mfma_f32_16x16x32_bf16(af, b1, acc1, 0, 0, 0);
            acc2 = __builtin_amdgcn_mfma_f32_16x16x32_bf16(af, b2, acc2, 0, 0, 0);
            acc3 = __builtin_amdgcn_mfma_f32_16x16x32_bf16(af, b3, acc3, 0, 0, 0);
            accl = __builtin_amdgcn_mfma_f32_16x16x32_bf16(af, ones, accl, 0, 0, 0);
        }
    }

    // row sums: D[row][col] identical over col; lanes with lo==0 own rows kg*4+reg
    if (lo == 0) {
        float* plw = pl + (size_t)blockIdx.y * NN + i0 + w * 16;
        #pragma unroll
        for (int reg = 0; reg < 4; ++reg) plw[kg * 4 + reg] = accl[reg];
    }

    // C/D layout (m89-verified): col = lane&15, row = (lane>>4)*4 + reg
    float* pa = pacc + ((size_t)blockIdx.y * NN + i0 + w * 16) * FOUT;
    #pragma unroll
    for (int reg = 0; reg < 4; ++reg) {
        const int orow = kg * 4 + reg;
        pa[(size_t)orow * FOUT + 0 * 16 + lo] = acc0[reg];
        pa[(size_t)orow * FOUT + 1 * 16 + lo] = acc1[reg];
        pa[(size_t)orow * FOUT + 2 * 16 + lo] = acc2[reg];
        pa[(size_t)orow * FOUT + 3 * 16 + lo] = acc3[reg];
    }
}

// ---------------------------------------------------------------------------
// Kernel 5: sum partials over j-splits, normalize, elu.
// ---------------------------------------------------------------------------
__global__ __launch_bounds__(256) void gat_reduce(
    const float* __restrict__ pacc, const float* __restrict__ pl,
    float* __restrict__ out, int JS)
{
    const int t = blockIdx.x * 256 + threadIdx.x;   // t < 8192*64
    const int i = t >> 6;
    float l = 0.f, v = 0.f;
    for (int js = 0; js < JS; ++js) {
        l += pl[(size_t)js * NN + i];
        v += pacc[(size_t)js * NN * FOUT + t];
    }
    const float r = v / l;
    out[t] = r > 0.f ? r : expm1f(r);
}

// ---------------------------------------------------------------------------
extern "C" void kernel_launch(void* const* d_in, const int* in_sizes, int n_in,
                              void* d_out, int out_size, void* d_ws, size_t ws_size,
                              hipStream_t stream)
{
    const float* inp = (const float*)d_in[0];
    const int*   adj = (const int*)d_in[1];
    const float* W   = (const float*)d_in[2];
    const float* a   = (const float*)d_in[3];
    float* out = (float*)d_out;

    // workspace carve-up
    char* ws = (char*)d_ws;
    unsigned short* ht = (unsigned short*)ws; ws += (size_t)FOUT * NN * 2;   // 1 MB
    u64* mask = (u64*)ws; ws += (size_t)NN * NT * 8;                         // 8 MB
    float* s1  = (float*)ws; ws += (size_t)NN * 4;
    float* s2  = (float*)ws; ws += (size_t)NN * 4;
    float* e1v = (float*)ws; ws += (size_t)NN * 4;
    float* e2v = (float*)ws; ws += (size_t)NN * 4;
    float* s2m = (float*)ws; ws += 256;
    const size_t fixed = (size_t)(ws - (char*)d_ws);

    int JS = 8;
    while (JS > 1 && fixed + (size_t)JS * NN * 4ull * (FOUT + 1) > ws_size) JS >>= 1;
    const int jlen = NN / JS;

    float* pl   = (float*)ws; ws += (size_t)JS * NN * 4;
    float* pacc = (float*)ws;

    gat_mask  <<<(NN * (NN / 32)) / 256, 256, 0, stream>>>(adj, (unsigned*)mask);
    gat_prep  <<<NN / 4, 256, 0, stream>>>(inp, W, a, ht, s1, s2, e1v, e2v);
    gat_s2max <<<1, 1024, 0, stream>>>(s2, s2m);
    gat_attn  <<<dim3(NN / 64, JS), 256, 0, stream>>>(mask, ht, s1, e1v, e2v, s2m, pacc, pl, jlen);
    gat_reduce<<<(NN * FOUT) / 256, 256, 0, stream>>>(pacc, pl, out, JS);
}

// Round 6
// 149.999 us; speedup vs baseline: 1.0193x; 1.0193x over previous
//
#include <hip/hip_runtime.h>

typedef __attribute__((ext_vector_type(8))) short short8;
typedef __attribute__((ext_vector_type(4))) float f32x4;
typedef __attribute__((ext_vector_type(4))) int   i32x4;
typedef unsigned long long u64;

#define NN 8192
#define FIN 128
#define FOUT 64
#define NW (NN / 32)          // 256 u32 mask words per row
#define LRELU_ALPHA 0.2f

__device__ __forceinline__ unsigned short f2bf(float x) {
    unsigned u = __float_as_uint(x);
    unsigned r = (u + 0x7FFFu + ((u >> 16) & 1u)) >> 16;  // RNE
    return (unsigned short)r;
}

// ---------------------------------------------------------------------------
// Kernel 1: h = inp @ W ; s1 = h@a1 ; s2 = h@a2 ;
//   ht[f][i] = bf16(h[i][f]) ; e1v[i]=exp(s2_i) ; e2v[i]=exp(alpha*s2_i)
// ---------------------------------------------------------------------------
__global__ __launch_bounds__(256) void gat_prep(
    const float* __restrict__ inp, const float* __restrict__ W,
    const float* __restrict__ a,
    unsigned short* __restrict__ ht, float* __restrict__ s1, float* __restrict__ s2,
    float* __restrict__ e1v, float* __restrict__ e2v)
{
    __shared__ float Wl[FIN * FOUT];   // 32 KB
    __shared__ float il[4 * FIN];      // 2 KB
    const int t = threadIdx.x;
    const int i0 = blockIdx.x * 4;

    #pragma unroll
    for (int k = 0; k < (FIN * FOUT) / 256; ++k)
        Wl[t + 256 * k] = W[t + 256 * k];
    #pragma unroll
    for (int k = 0; k < (4 * FIN) / 256; ++k)
        il[t + 256 * k] = inp[(size_t)i0 * FIN + t + 256 * k];
    __syncthreads();

    const int r = t >> 6;        // local row 0..3
    const int f = t & 63;        // output feature
    float acc = 0.f;
    #pragma unroll 8
    for (int k = 0; k < FIN; ++k)
        acc = fmaf(il[r * FIN + k], Wl[k * FOUT + f], acc);

    float v1 = acc * a[f];
    float v2 = acc * a[FOUT + f];
    #pragma unroll
    for (int off = 32; off; off >>= 1) {
        v1 += __shfl_xor(v1, off, 64);
        v2 += __shfl_xor(v2, off, 64);
    }
    const int i = i0 + r;
    if (f == 0) {
        s1[i] = v1;
        s2[i] = v2;
        e1v[i] = __expf(v2);
        e2v[i] = __expf(LRELU_ALPHA * v2);
    }
    ht[(size_t)f * NN + i] = f2bf(acc);
}

// ---------------------------------------------------------------------------
// Kernel 2: s2max = max_j s2[j]
// ---------------------------------------------------------------------------
__global__ __launch_bounds__(1024) void gat_s2max(const float* __restrict__ s2,
                                                  float* __restrict__ s2m)
{
    __shared__ float red[16];
    float m = -1e30f;
    for (int idx = threadIdx.x; idx < NN; idx += 1024) m = fmaxf(m, s2[idx]);
    #pragma unroll
    for (int off = 32; off; off >>= 1) m = fmaxf(m, __shfl_xor(m, off, 64));
    if ((threadIdx.x & 63) == 0) red[threadIdx.x >> 6] = m;
    __syncthreads();
    if (threadIdx.x == 0) {
        float mm = red[0];
        #pragma unroll
        for (int k = 1; k < 16; ++k) mm = fmaxf(mm, red[k]);
        s2m[0] = mm;
    }
}

// ---------------------------------------------------------------------------
// Kernel 3: adj (256 MB int32) -> bitmask (8 MB), natural bit order,
// ballot-free: one thread per 32-col word, 128 B contiguous per thread.
// ---------------------------------------------------------------------------
__global__ __launch_bounds__(256) void gat_mask(const int* __restrict__ adj,
                                                unsigned* __restrict__ mask)
{
    const int gid = blockIdx.x * 256 + threadIdx.x;   // word index, 0 .. 2M-1
    const int* p = adj + (size_t)gid * 32;

    i32x4 v[8];
    #pragma unroll
    for (int q = 0; q < 8; ++q)
        v[q] = *(const i32x4*)(p + q * 4);

    unsigned m = 0;
    #pragma unroll
    for (int q = 0; q < 8; ++q) {
        #pragma unroll
        for (int e = 0; e < 4; ++e)
            m |= (v[q][e] > 0 ? 1u : 0u) << (q * 4 + e);
    }
    mask[gid] = m;
}

// ---------------------------------------------------------------------------
// Kernel 4 (hot): mask-driven attention, register double-buffered (T14):
// STAGE(next 32-col step) issued before COMPUTE(current) so ht/E/mask loads
// stay in flight across a full compute phase. p = mask ? max(c1*e1, c2*e2) : 0
// (lrelu = max(x, ax), exp monotone => exp(lrelu(x)-Mi) = max(c1 e1, c2 e2)).
// Block: 256 = 4 waves x 16 rows. Grid: (128, JS).
// ---------------------------------------------------------------------------
#define STAGE(P, uu) do {                                                   \
    P##_m   = mrow[(uu)];                                                   \
    const int vg_ = (uu) * 32 + 8 * kg;                                     \
    P##_e1a = *(const f32x4*)(e1v + vg_);                                   \
    P##_e1b = *(const f32x4*)(e1v + vg_ + 4);                               \
    P##_e2a = *(const f32x4*)(e2v + vg_);                                   \
    P##_e2b = *(const f32x4*)(e2v + vg_ + 4);                               \
    const unsigned short* hb_ = ht + vg_;                                   \
    P##_b0  = *(const short8*)(hb_ + (size_t)(0 * 16 + lo) * NN);           \
    P##_b1  = *(const short8*)(hb_ + (size_t)(1 * 16 + lo) * NN);           \
    P##_b2  = *(const short8*)(hb_ + (size_t)(2 * 16 + lo) * NN);           \
    P##_b3  = *(const short8*)(hb_ + (size_t)(3 * 16 + lo) * NN);           \
} while (0)

#define COMPUTE(P) do {                                                     \
    const unsigned mb_ = (P##_m >> (8 * kg)) & 0xffu;                       \
    float p_[8];                                                            \
    _Pragma("unroll")                                                       \
    for (int e = 0; e < 8; ++e) {                                           \
        const float e1_ = (e < 4) ? P##_e1a[e] : P##_e1b[e - 4];            \
        const float e2_ = (e < 4) ? P##_e2a[e] : P##_e2b[e - 4];            \
        const float pv_ = fmaxf(c1 * e1_, c2 * e2_);                        \
        p_[e] = ((mb_ >> e) & 1u) ? pv_ : 0.f;                              \
        lsum += p_[e];                                                      \
    }                                                                       \
    union { short8 s8; unsigned u4[4]; } afu_;                              \
    _Pragma("unroll")                                                       \
    for (int q = 0; q < 4; ++q) {                                           \
        unsigned rr_;                                                       \
        asm("v_cvt_pk_bf16_f32 %0, %1, %2"                                  \
            : "=v"(rr_) : "v"(p_[2 * q]), "v"(p_[2 * q + 1]));              \
        afu_.u4[q] = rr_;                                                   \
    }                                                                       \
    const short8 af_ = afu_.s8;                                             \
    acc0 = __builtin_amdgcn_mfma_f32_16x16x32_bf16(af_, P##_b0, acc0, 0,0,0); \
    acc1 = __builtin_amdgcn_mfma_f32_16x16x32_bf16(af_, P##_b1, acc1, 0,0,0); \
    acc2 = __builtin_amdgcn_mfma_f32_16x16x32_bf16(af_, P##_b2, acc2, 0,0,0); \
    acc3 = __builtin_amdgcn_mfma_f32_16x16x32_bf16(af_, P##_b3, acc3, 0,0,0); \
} while (0)

__global__ __launch_bounds__(256, 4) void gat_attn(
    const unsigned* __restrict__ mask, const unsigned short* __restrict__ ht,
    const float* __restrict__ s1, const float* __restrict__ e1v,
    const float* __restrict__ e2v, const float* __restrict__ s2m,
    float* __restrict__ pacc, float* __restrict__ pl, int jlen)
{
    const int w    = threadIdx.x >> 6;   // wave 0..3 -> rows w*16..w*16+15
    const int lane = threadIdx.x & 63;
    const int lo   = lane & 15;          // A-frag row / B-frag col
    const int kg   = lane >> 4;          // k-group 0..3
    const int i0   = blockIdx.x * 64;
    const int i    = i0 + w * 16 + lo;   // this lane's attention row

    const float s1v = s1[i];
    const float mm  = s1v + s2m[0];
    const float Mi  = fmaxf(mm, LRELU_ALPHA * mm);      // >= max_j e_ij
    const float c1  = __expf(s1v - Mi);
    const float c2  = __expf(LRELU_ALPHA * s1v - Mi);

    const unsigned* mrow = mask + (size_t)i * NW;
    const int u0 = (blockIdx.y * jlen) >> 5;   // 32-col steps
    const int nu = jlen >> 5;

    f32x4 acc0 = {0.f,0.f,0.f,0.f}, acc1 = {0.f,0.f,0.f,0.f};
    f32x4 acc2 = {0.f,0.f,0.f,0.f}, acc3 = {0.f,0.f,0.f,0.f};
    float lsum = 0.f;

    unsigned A_m, B_m;
    f32x4 A_e1a, A_e1b, A_e2a, A_e2b, B_e1a, B_e1b, B_e2a, B_e2b;
    short8 A_b0, A_b1, A_b2, A_b3, B_b0, B_b1, B_b2, B_b3;

    STAGE(A, u0);
    for (int k = 0; k < nu / 2 - 1; ++k) {
        const int u = u0 + 2 * k;
        STAGE(B, u + 1);
        COMPUTE(A);
        STAGE(A, u + 2);
        COMPUTE(B);
    }
    STAGE(B, u0 + nu - 1);
    COMPUTE(A);
    COMPUTE(B);

    // row-sum of p across the 4 k-groups
    lsum += __shfl_xor(lsum, 16, 64);
    lsum += __shfl_xor(lsum, 32, 64);
    if (kg == 0)
        pl[(size_t)blockIdx.y * NN + i] = lsum;

    // C/D layout (m89-verified): col = lane&15, row = (lane>>4)*4 + reg
    float* pa = pacc + ((size_t)blockIdx.y * NN + i0 + w * 16) * FOUT;
    #pragma unroll
    for (int reg = 0; reg < 4; ++reg) {
        const int orow = kg * 4 + reg;
        pa[(size_t)orow * FOUT + 0 * 16 + lo] = acc0[reg];
        pa[(size_t)orow * FOUT + 1 * 16 + lo] = acc1[reg];
        pa[(size_t)orow * FOUT + 2 * 16 + lo] = acc2[reg];
        pa[(size_t)orow * FOUT + 3 * 16 + lo] = acc3[reg];
    }
}

// ---------------------------------------------------------------------------
// Kernel 5: sum partials over j-splits, normalize, elu.
// ---------------------------------------------------------------------------
__global__ __launch_bounds__(256) void gat_reduce(
    const float* __restrict__ pacc, const float* __restrict__ pl,
    float* __restrict__ out, int JS)
{
    const int t = blockIdx.x * 256 + threadIdx.x;   // t < 8192*64
    const int i = t >> 6;
    float l = 0.f, v = 0.f;
    for (int js = 0; js < JS; ++js) {
        l += pl[(size_t)js * NN + i];
        v += pacc[(size_t)js * NN * FOUT + t];
    }
    const float r = v / l;
    out[t] = r > 0.f ? r : expm1f(r);
}

// ---------------------------------------------------------------------------
extern "C" void kernel_launch(void* const* d_in, const int* in_sizes, int n_in,
                              void* d_out, int out_size, void* d_ws, size_t ws_size,
                              hipStream_t stream)
{
    const float* inp = (const float*)d_in[0];
    const int*   adj = (const int*)d_in[1];
    const float* W   = (const float*)d_in[2];
    const float* a   = (const float*)d_in[3];
    float* out = (float*)d_out;

    // workspace carve-up
    char* ws = (char*)d_ws;
    unsigned short* ht = (unsigned short*)ws; ws += (size_t)FOUT * NN * 2;   // 1 MB
    unsigned* mask = (unsigned*)ws; ws += (size_t)NN * NW * 4;               // 8 MB
    float* s1  = (float*)ws; ws += (size_t)NN * 4;
    float* s2  = (float*)ws; ws += (size_t)NN * 4;
    float* e1v = (float*)ws; ws += (size_t)NN * 4;
    float* e2v = (float*)ws; ws += (size_t)NN * 4;
    float* s2m = (float*)ws; ws += 256;
    const size_t fixed = (size_t)(ws - (char*)d_ws);

    int JS = 8;
    while (JS > 1 && fixed + (size_t)JS * NN * 4ull * (FOUT + 1) > ws_size) JS >>= 1;
    const int jlen = NN / JS;

    float* pl   = (float*)ws; ws += (size_t)JS * NN * 4;
    float* pacc = (float*)ws;

    gat_mask  <<<(NN * NW) / 256, 256, 0, stream>>>(adj, mask);
    gat_prep  <<<NN / 4, 256, 0, stream>>>(inp, W, a, ht, s1, s2, e1v, e2v);
    gat_s2max <<<1, 1024, 0, stream>>>(s2, s2m);
    gat_attn  <<<dim3(NN / 64, JS), 256, 0, stream>>>(mask, ht, s1, e1v, e2v, s2m, pacc, pl, jlen);
    gat_reduce<<<(NN * FOUT) / 256, 256, 0, stream>>>(pacc, pl, out, JS);
}